// Round 3
// baseline (128.276 us; speedup 1.0000x reference)
//
#include <hip/hip_runtime.h>
#include <hip/hip_bf16.h>

#define NN 3072
#define RR 8
#define I_PER_BLOCK 4

typedef float f4 __attribute__((ext_vector_type(4)));

__global__ __launch_bounds__(256) void frd_kernel(
    const float* __restrict__ z,       // [N, R]
    const int*   __restrict__ seg,     // [N, N]
    const int*   __restrict__ cls,     // [N]
    const int*   __restrict__ batch,   // [N]
    float*       __restrict__ out)     // [N, N, R]
{
    const int j  = blockIdx.x * 256 + threadIdx.x;   // coalesced along j
    const int i0 = blockIdx.y * I_PER_BLOCK;         // wave-uniform rows

    // per-j data: loaded once, reused for all 4 rows
    const int  cj = cls[j];
    const int  bj = batch[j];
    const bool jm = (cj < 24);                       // labels in [0,27)
    const f4* zjp = (const f4*)(z + (long long)j * RR);
    const f4 b0 = zjp[0], b1 = zjp[1];

#pragma unroll
    for (int ii = 0; ii < I_PER_BLOCK; ++ii) {
        const int i = i0 + ii;                       // uniform -> scalar loads
        const int ci = cls[i];
        const int bi = batch[i];
        const f4* zip = (const f4*)(z + (long long)i * RR);
        const f4 a0 = zip[0], a1 = zip[1];

        const long long pidx = (long long)i * NN + j;
        const int s = __builtin_nontemporal_load(seg + pidx);

        // seg_matrix in {0,1}; +eye means diagonal never masked -> (s==0 && i!=j)
        const bool pm = (s == 0) & (i != j) & (ci < 24) & jm & (bi == bj);

        f4 lo, hi;
        lo.x = pm ? a0.x * b0.x : 1.0f;
        lo.y = pm ? a0.y * b0.y : 0.0f;
        lo.z = pm ? a0.z * b0.z : 0.0f;
        lo.w = pm ? a0.w * b0.w : 0.0f;
        hi.x = pm ? a1.x * b1.x : 0.0f;
        hi.y = pm ? a1.y * b1.y : 0.0f;
        hi.z = pm ? a1.z * b1.z : 0.0f;
        hi.w = pm ? a1.w * b1.w : 0.0f;

        f4* o = (f4*)(out + pidx * RR);
        __builtin_nontemporal_store(lo, o);
        __builtin_nontemporal_store(hi, o + 1);
    }
}

extern "C" void kernel_launch(void* const* d_in, const int* in_sizes, int n_in,
                              void* d_out, int out_size, void* d_ws, size_t ws_size,
                              hipStream_t stream) {
    const float* z     = (const float*)d_in[0];
    const int*   seg   = (const int*)d_in[1];
    const int*   cls   = (const int*)d_in[2];
    const int*   batch = (const int*)d_in[3];
    float* out = (float*)d_out;

    dim3 grid(NN / 256, NN / I_PER_BLOCK);   // (12, 768)
    frd_kernel<<<grid, dim3(256), 0, stream>>>(z, seg, cls, batch, out);
}